// Round 4
// baseline (2168.758 us; speedup 1.0000x reference)
//
#include <hip/hip_runtime.h>
#include <math.h>
#include <stdint.h>

#define BB 1024     // batch
#define DD 512      // hidden
#define VV 10000    // vocab
#define TT 20       // steps
#define NW 50       // allowed words

// ---------------------------------------------------------------------------
// threefry2x32 block (matches jax/_src/prng.py rotation schedule exactly)
// ---------------------------------------------------------------------------
__host__ __device__ __forceinline__ void tf2x32(uint32_t k0, uint32_t k1,
                                                uint32_t x0, uint32_t x1,
                                                uint32_t& o0, uint32_t& o1) {
  uint32_t ks2 = k0 ^ k1 ^ 0x1BD11BDAu;
  x0 += k0; x1 += k1;
#define ROTL(x,r) (((x)<<(r))|((x)>>(32-(r))))
#define RND(r) { x0 += x1; x1 = ROTL(x1,(r)); x1 ^= x0; }
  RND(13) RND(15) RND(26) RND(6)   x0 += k1;  x1 += ks2 + 1u;
  RND(17) RND(29) RND(16) RND(24)  x0 += ks2; x1 += k0 + 2u;
  RND(13) RND(15) RND(26) RND(6)   x0 += k0;  x1 += k1 + 3u;
  RND(17) RND(29) RND(16) RND(24)  x0 += k1;  x1 += ks2 + 4u;
  RND(13) RND(15) RND(26) RND(6)   x0 += ks2; x1 += k0 + 5u;
#undef RND
#undef ROTL
  o0 = x0; o1 = x1;
}

// random-bits layout:
// 0 = partitionable, lo word o1                                    [FAILED r1]
// 1 = legacy original split-iota-halves layout                     [FAILED r2]
// 2 = partitionable, hi word o0                                    [FAILED r3]
// 5 = partitionable, XOR fold o0^o1                                [this round]
#define RB_MODE 5

__device__ __forceinline__ float wave_sum(float v) {
#pragma unroll
  for (int o = 32; o > 0; o >>= 1) v += __shfl_xor(v, o, 64);
  return v;
}
__device__ __forceinline__ float wave_max(float v) {
#pragma unroll
  for (int o = 32; o > 0; o >>= 1) v = fmaxf(v, __shfl_xor(v, o, 64));
  return v;
}

__device__ __forceinline__ float gelu_f(float x) {
  // jax.nn.gelu(approximate=False): x * (erf(x / sqrt2_f32) + 1) / 2
  float u = x / 1.4142135623730951f;
  float e = (float)erf((double)u);      // correctly-rounded f32 erf
  return x * (e + 1.0f) * 0.5f;
}

// ---------------------------------------------------------------------------
// fp32 tiled GEMM: C[M,N] = act(A[M,K] @ W[K,N] + bias) (+res)
// BM=BN=64, BK=16, 256 threads, 4x4 micro-tile.
// ---------------------------------------------------------------------------
template<int ACT, bool RES, bool CONCAT>
__device__ __forceinline__ void gemm_body(
    const float* __restrict__ A, const float* __restrict__ A2, int K1,
    const float* __restrict__ W, int ldw, const float* __restrict__ bias,
    const float* __restrict__ res, float* __restrict__ C, int N, int K)
{
  __shared__ float As[16][68];
  __shared__ float Ws[16][68];
  const int bm = blockIdx.x * 64;
  const int bn = blockIdx.y * 64;
  const int tid = threadIdx.x;
  const int tr = (tid >> 4) << 2;
  const int tc = (tid & 15) << 2;
  float acc[4][4] = {};
  for (int k0 = 0; k0 < K; k0 += 16) {
#pragma unroll
    for (int i = 0; i < 4; i++) {
      int lin = tid + 256 * i;
      int m = lin >> 4, kk = lin & 15;
      int gk = k0 + kk;
      float v;
      if (CONCAT) {
        v = (gk < K1) ? A[(bm + m) * K1 + gk] : A2[(bm + m) * (K - K1) + (gk - K1)];
      } else {
        v = A[(bm + m) * K + gk];
      }
      As[kk][m] = v;
    }
#pragma unroll
    for (int i = 0; i < 4; i++) {
      int lin = tid + 256 * i;
      int kk = lin >> 6, n = lin & 63;
      Ws[kk][n] = W[(k0 + kk) * ldw + bn + n];
    }
    __syncthreads();
#pragma unroll
    for (int kk = 0; kk < 16; kk++) {
      float av[4], bv[4];
#pragma unroll
      for (int i = 0; i < 4; i++) av[i] = As[kk][tr + i];
#pragma unroll
      for (int j = 0; j < 4; j++) bv[j] = Ws[kk][tc + j];
#pragma unroll
      for (int i = 0; i < 4; i++)
#pragma unroll
        for (int j = 0; j < 4; j++)
          acc[i][j] = fmaf(av[i], bv[j], acc[i][j]);
    }
    __syncthreads();
  }
#pragma unroll
  for (int i = 0; i < 4; i++) {
    int m = bm + tr + i;
#pragma unroll
    for (int j = 0; j < 4; j++) {
      int n = bn + tc + j;
      float v = acc[i][j] + bias[n];
      if (ACT == 1) v = gelu_f(v);
      if (ACT == 2) v = (float)tanh((double)v);
      if (RES) v = v + res[(size_t)m * N + n];
      C[(size_t)m * N + n] = v;
    }
  }
}

template<int ACT, bool RES, bool CONCAT>
__global__ __launch_bounds__(256) void sgemm_k(
    const float* __restrict__ A, const float* __restrict__ A2, int K1,
    const float* __restrict__ W, int ldw, const float* __restrict__ bias,
    const float* __restrict__ res, float* __restrict__ C, int N, int K)
{
  gemm_body<ACT, RES, CONCAT>(A, A2, K1, W, ldw, bias, res, C, N, K);
}

// dual GEMM: z=0 -> gi = hx@gwi+gbi ; z=1 -> gh = ix@gwh+gbh
__global__ __launch_bounds__(256) void sgemm_dual(
    const float* __restrict__ A0, const float* __restrict__ A1,
    const float* __restrict__ W0, const float* __restrict__ W1,
    const float* __restrict__ b0, const float* __restrict__ b1,
    float* __restrict__ C0, float* __restrict__ C1, int N, int K)
{
  const float* A = blockIdx.z ? A1 : A0;
  const float* W = blockIdx.z ? W1 : W0;
  const float* bs = blockIdx.z ? b1 : b0;
  float* C = blockIdx.z ? C1 : C0;
  gemm_body<0, false, false>(A, nullptr, 0, W, N, bs, nullptr, C, N, K);
}

// ---------------------------------------------------------------------------
// LayerNorm over D=512
// ---------------------------------------------------------------------------
template<bool AFFINE, bool ADD>
__global__ __launch_bounds__(256) void lnorm_k(
    const float* __restrict__ X, const float* __restrict__ X2,
    const float* __restrict__ g, const float* __restrict__ bt,
    float* __restrict__ Y)
{
  __shared__ float red[8];
  int row = blockIdx.x, tid = threadIdx.x;
  const float* x = X + (size_t)row * DD;
  float v0 = x[tid], v1 = x[tid + 256];
  if (ADD) {
    const float* x2 = X2 + (size_t)row * DD;
    v0 += x2[tid]; v1 += x2[tid + 256];
  }
  float s = wave_sum(v0 + v1);
  if ((tid & 63) == 0) red[tid >> 6] = s;
  __syncthreads();
  float mean = (red[0] + red[1] + red[2] + red[3]) * (1.0f / 512.0f);
  float d0 = v0 - mean, d1 = v1 - mean;
  float s2 = wave_sum(d0 * d0 + d1 * d1);
  if ((tid & 63) == 0) red[4 + (tid >> 6)] = s2;
  __syncthreads();
  float var = (red[4] + red[5] + red[6] + red[7]) * (1.0f / 512.0f);
  float rs = (float)(1.0 / sqrt((double)(var + 1e-5f)));
  float y0 = d0 * rs, y1 = d1 * rs;
  if (AFFINE) {
    y0 = y0 * g[tid] + bt[tid];
    y1 = y1 * g[tid + 256] + bt[tid + 256];
  }
  Y[(size_t)row * DD + tid] = y0;
  Y[(size_t)row * DD + tid + 256] = y1;
}

// ---------------------------------------------------------------------------
// GRU pointwise: torch gate order (r,z,n); hx_out = (1-z)*n + z*ix
// ---------------------------------------------------------------------------
__global__ __launch_bounds__(256) void gru_pw(
    const float* __restrict__ gi, const float* __restrict__ gh,
    const float* __restrict__ ix, float* __restrict__ hx)
{
  int idx = blockIdx.x * 256 + threadIdx.x;
  int b = idx >> 9, j = idx & 511;
  const float* gib = gi + (size_t)b * 1536;
  const float* ghb = gh + (size_t)b * 1536;
  float r = (float)(1.0 / (1.0 + exp(-(double)(gib[j] + ghb[j]))));
  float z = (float)(1.0 / (1.0 + exp(-(double)(gib[DD + j] + ghb[DD + j]))));
  float narg = gib[2 * DD + j] + r * ghb[2 * DD + j];
  float n = (float)tanh((double)narg);
  hx[idx] = (1.0f - z) * n + z * ix[idx];
}

// ---------------------------------------------------------------------------
// Fused actor/critic heads + jax categorical sampling. 1 wave per row.
// ---------------------------------------------------------------------------
__global__ __launch_bounds__(64) void head_sample(
    const float* __restrict__ hx,
    const float* __restrict__ a1w, const float* __restrict__ a1b,
    const float* __restrict__ a2w, const float* __restrict__ a2b,
    const float* __restrict__ a3w, const float* __restrict__ a3b,
    const float* __restrict__ c1w, const float* __restrict__ c1b,
    const float* __restrict__ c2w, const float* __restrict__ c2b,
    const float* __restrict__ c3w, const float* __restrict__ c3b,
    const float* __restrict__ wmask,
    const float* __restrict__ emb,
    float* __restrict__ ix, float* __restrict__ out,
    int t, uint32_t fk0, uint32_t fk1)
{
  int b = blockIdx.x;
  int lane = threadIdx.x;
  __shared__ float sh[DD];
  __shared__ float st1[64], st2[64], sc1[64];
  const float* hr = hx + (size_t)b * DD;
  for (int i = lane; i < DD; i += 64) sh[i] = hr[i];
  __syncthreads();

  float aa0 = 0, aa1 = 0, aa2 = 0, aa3 = 0, ca0 = 0, ca1 = 0, ca2 = 0, ca3 = 0;
  for (int k = 0; k < DD; k += 4) {
    float h0 = sh[k], h1 = sh[k + 1], h2 = sh[k + 2], h3 = sh[k + 3];
    aa0 = fmaf(h0, a1w[(k + 0) * 64 + lane], aa0);
    aa1 = fmaf(h1, a1w[(k + 1) * 64 + lane], aa1);
    aa2 = fmaf(h2, a1w[(k + 2) * 64 + lane], aa2);
    aa3 = fmaf(h3, a1w[(k + 3) * 64 + lane], aa3);
    ca0 = fmaf(h0, c1w[(k + 0) * 64 + lane], ca0);
    ca1 = fmaf(h1, c1w[(k + 1) * 64 + lane], ca1);
    ca2 = fmaf(h2, c1w[(k + 2) * 64 + lane], ca2);
    ca3 = fmaf(h3, c1w[(k + 3) * 64 + lane], ca3);
  }
  st1[lane] = (float)tanh((double)(((aa0 + aa1) + (aa2 + aa3)) + a1b[lane]));
  sc1[lane] = (float)tanh((double)(((ca0 + ca1) + (ca2 + ca3)) + c1b[lane]));
  __syncthreads();

  float a2acc = 0, c2acc = 0;
  for (int k = 0; k < 64; k++) {
    a2acc = fmaf(st1[k], a2w[k * 64 + lane], a2acc);
    c2acc = fmaf(sc1[k], c2w[k * 64 + lane], c2acc);
  }
  st2[lane] = (float)tanh((double)(a2acc + a2b[lane]));
  float t2c = (float)tanh((double)(c2acc + c2b[lane]));
  __syncthreads();

  float val = wave_sum(t2c * c3w[lane]) + c3b[0];

  float lg = -INFINITY;
  if (lane < NW) {
    float s = 0;
    for (int k = 0; k < 64; k++) s = fmaf(st2[k], a3w[k * VV + lane], s);
    lg = (s + a3b[lane]) + wmask[lane];
  }

  float m = wave_max(lg);
  float shf = 0.f, e = 0.f;
  if (lane < NW) { shf = lg - m; e = (float)exp((double)shf); }
  float se = wave_sum(e);
  float lse = (float)log((double)se);
  float logp = shf - lse;
  float term = 0.f;
  if (lane < NW) { float p = (float)exp((double)logp); term = p * logp; }
  float ent = -wave_sum(term);

  float score = -INFINITY;
  if (lane < NW) {
    uint32_t i = (uint32_t)b * (uint32_t)VV + (uint32_t)lane;
    uint32_t o0, o1, bits;
#if RB_MODE == 0
    tf2x32(fk0, fk1, 0u, i, o0, o1);
    bits = o1;
#elif RB_MODE == 1
    const uint32_t H = (uint32_t)(BB / 2) * (uint32_t)VV;
    if (b < BB / 2) { tf2x32(fk0, fk1, i, i + H, o0, o1); bits = o0; }
    else            { tf2x32(fk0, fk1, i - H, i, o0, o1); bits = o1; }
#elif RB_MODE == 2
    tf2x32(fk0, fk1, 0u, i, o0, o1);
    bits = o0;
#else   // 5: XOR fold of the two block outputs
    tf2x32(fk0, fk1, 0u, i, o0, o1);
    bits = o0 ^ o1;
#endif
    uint32_t mant = bits >> 9;
    float u = (mant == 0u) ? 1.17549435e-38f
                           : (float)mant * 1.1920928955078125e-7f;
    float l1 = (float)log((double)u);
    float l2 = (float)log((double)(-l1));
    float gmb = -l2;
    score = gmb + logp;
  }

  float best = score; int bi = lane;
#pragma unroll
  for (int off = 32; off > 0; off >>= 1) {
    float ob = __shfl_xor(best, off, 64);
    int oi = __shfl_xor(bi, off, 64);
    if (ob > best || (ob == best && oi < bi)) { best = ob; bi = oi; }
  }
  float lp = __shfl(logp, bi, 64);

  if (lane == 0) {
    out[(size_t)b * TT + t] = (float)bi;
    out[(size_t)BB * TT + (size_t)b * TT + t] = lp;
    out[2 * (size_t)BB * TT + (size_t)b * TT + t] = ent;
    out[3 * (size_t)BB * TT + (size_t)b * TT + t] = val;
  }

  const float* er = emb + (size_t)bi * DD;
  float* ixr = ix + (size_t)b * DD;
  for (int i2 = lane; i2 < DD; i2 += 64) ixr[i2] = er[i2];
}

// ---------------------------------------------------------------------------
// Diagnostic channel: write `code` to every out element -> reported absmax
// reveals the contract violation. slot = floor(absmax/1e6):
//  1: n_in != 34 (detail = n_in)
//  2: in_sizes mismatch (detail = idx*1e4 + size%1e4)
//  3: out_size != 81920 (detail = out_size%1e6)
//  4: ws_size < 24 MiB (detail = ws KiB)
// ---------------------------------------------------------------------------
__global__ __launch_bounds__(256) void diag_k(float* out, float code, int n) {
  int i = blockIdx.x * 256 + threadIdx.x;
  if (i < n) out[i] = code;
}

// ---------------------------------------------------------------------------
extern "C" void kernel_launch(void* const* d_in, const int* in_sizes, int n_in,
                              void* d_out, int out_size, void* d_ws, size_t ws_size,
                              hipStream_t stream) {
  static const int EXP_SIZES[34] = {
    2097152, 262144, 1179648, 512, 262144, 512, 262144, 512, 262144, 512,
    262144, 512, 512, 512, 262144, 512, 5120000, 786432, 786432, 1536,
    1536, 32768, 64, 4096, 64, 640000, 10000, 32768, 64, 4096,
    64, 64, 1, 10000 };

  double code = 0.0;
  if (n_in != 34) {
    code = 1e6 + (double)n_in;
  } else {
    for (int i = 0; i < 34; i++) {
      if (in_sizes[i] != EXP_SIZES[i]) {
        code = 2e6 + (double)i * 1e4 + (double)(in_sizes[i] % 10000);
        break;
      }
    }
  }
  if (code == 0.0 && out_size != 4 * BB * TT)
    code = 3e6 + (double)(out_size % 1000000);
  if (code == 0.0 && ws_size < (size_t)24 * 1024 * 1024) {
    size_t kb = ws_size / 1024; if (kb > 999999) kb = 999999;
    code = 4e6 + (double)kb;
  }
  if (code != 0.0) {
    diag_k<<<(out_size + 255) / 256, 256, 0, stream>>>((float*)d_out, (float)code, out_size);
    return;
  }

  const float* image = (const float*)d_in[0];
  const float* boxf  = (const float*)d_in[1];
  const float* fr_w  = (const float*)d_in[2];
  const float* fr_b  = (const float*)d_in[3];
  const float* d1a_w = (const float*)d_in[4];
  const float* d1a_b = (const float*)d_in[5];
  const float* d1b_w = (const float*)d_in[6];
  const float* d1b_b = (const float*)d_in[7];
  const float* d2a_w = (const float*)d_in[8];
  const float* d2a_b = (const float*)d_in[9];
  const float* d2b_w = (const float*)d_in[10];
  const float* d2b_b = (const float*)d_in[11];
  const float* ln_g  = (const float*)d_in[12];
  const float* ln_b  = (const float*)d_in[13];
  const float* eo_w  = (const float*)d_in[14];
  const float* eo_b  = (const float*)d_in[15];
  const float* emb   = (const float*)d_in[16];
  const float* gwi   = (const float*)d_in[17];
  const float* gwh   = (const float*)d_in[18];
  const float* gbi   = (const float*)d_in[19];
  const float* gbh   = (const float*)d_in[20];
  const float* a1w   = (const float*)d_in[21];
  const float* a1b   = (const float*)d_in[22];
  const float* a2w   = (const float*)d_in[23];
  const float* a2b   = (const float*)d_in[24];
  const float* a3w   = (const float*)d_in[25];
  const float* a3b   = (const float*)d_in[26];
  const float* c1w   = (const float*)d_in[27];
  const float* c1b   = (const float*)d_in[28];
  const float* c2w   = (const float*)d_in[29];
  const float* c2b   = (const float*)d_in[30];
  const float* c3w   = (const float*)d_in[31];
  const float* c3b   = (const float*)d_in[32];
  const float* wmask = (const float*)d_in[33];

  float* ws = (float*)d_ws;
  const size_t R = (size_t)BB * DD;   // 524288 floats
  // rollout layout (8R total = 16 MiB):
  float* hx = ws;            // [B,512]
  float* ix = ws + R;        // [B,512]
  float* gi = ws + 2 * R;    // [B,1536]
  float* gh = ws + 5 * R;    // [B,1536]
  // encoder scratch (inside gi/gh space, dead once rollout starts):
  float* P = gh;             // x0
  float* Q = gh + R;         // tA
  float* S = gh + 2 * R;     // tB
  float* U = gi;             // y / x
  float* out = (float*)d_out;

  dim3 blk(256);
  // encoder
  sgemm_k<0, false, true><<<dim3(16, 8), blk, 0, stream>>>(image, boxf, 2048, fr_w, 512, fr_b, nullptr, P, 512, 2304);
  lnorm_k<false, false><<<BB, blk, 0, stream>>>(P, nullptr, nullptr, nullptr, Q);
  sgemm_k<1, false, false><<<dim3(16, 8), blk, 0, stream>>>(Q, nullptr, 0, d1a_w, 512, d1a_b, nullptr, S, 512, 512);
  sgemm_k<0, false, false><<<dim3(16, 8), blk, 0, stream>>>(S, nullptr, 0, d1b_w, 512, d1b_b, nullptr, U, 512, 512);
  lnorm_k<false, true><<<BB, blk, 0, stream>>>(U, P, nullptr, nullptr, Q);
  sgemm_k<1, false, false><<<dim3(16, 8), blk, 0, stream>>>(Q, nullptr, 0, d2a_w, 512, d2a_b, nullptr, S, 512, 512);
  sgemm_k<0, true, false><<<dim3(16, 8), blk, 0, stream>>>(S, nullptr, 0, d2b_w, 512, d2b_b, P, U, 512, 512);
  lnorm_k<true, false><<<BB, blk, 0, stream>>>(U, nullptr, ln_g, ln_b, Q);
  sgemm_k<0, false, false><<<dim3(16, 8), blk, 0, stream>>>(Q, nullptr, 0, eo_w, 512, eo_b, nullptr, hx, 512, 512);
  hipMemsetAsync(ix, 0, R * sizeof(float), stream);

  // rollout
  for (int t = 0; t < TT; t++) {
    uint32_t fk0, fk1;
    tf2x32(0u, 1u, 0u, (uint32_t)t, fk0, fk1);   // fold_in(key(1), t)
    sgemm_dual<<<dim3(16, 24, 2), blk, 0, stream>>>(hx, ix, gwi, gwh, gbi, gbh, gi, gh, 1536, 512);
    gru_pw<<<2048, blk, 0, stream>>>(gi, gh, ix, hx);
    head_sample<<<BB, dim3(64), 0, stream>>>(hx, a1w, a1b, a2w, a2b, a3w, a3b,
                                             c1w, c1b, c2w, c2b, c3w, c3b,
                                             wmask, emb, ix, out, t, fk0, fk1);
  }
}

// Round 5
// 1652.224 us; speedup vs baseline: 1.3126x; 1.3126x over previous
//
#include <hip/hip_runtime.h>
#include <math.h>
#include <stdint.h>

#define BB 1024     // batch
#define DD 512      // hidden
#define VV 10000    // vocab
#define TT 20       // steps
#define NW 50       // allowed words

// ---------------------------------------------------------------------------
// threefry2x32 block (matches jax/_src/prng.py rotation schedule exactly)
// ---------------------------------------------------------------------------
__host__ __device__ __forceinline__ void tf2x32(uint32_t k0, uint32_t k1,
                                                uint32_t x0, uint32_t x1,
                                                uint32_t& o0, uint32_t& o1) {
  uint32_t ks2 = k0 ^ k1 ^ 0x1BD11BDAu;
  x0 += k0; x1 += k1;
#define ROTL(x,r) (((x)<<(r))|((x)>>(32-(r))))
#define RND(r) { x0 += x1; x1 = ROTL(x1,(r)); x1 ^= x0; }
  RND(13) RND(15) RND(26) RND(6)   x0 += k1;  x1 += ks2 + 1u;
  RND(17) RND(29) RND(16) RND(24)  x0 += ks2; x1 += k0 + 2u;
  RND(13) RND(15) RND(26) RND(6)   x0 += k0;  x1 += k1 + 3u;
  RND(17) RND(29) RND(16) RND(24)  x0 += k1;  x1 += ks2 + 4u;
  RND(13) RND(15) RND(26) RND(6)   x0 += ks2; x1 += k0 + 5u;
#undef RND
#undef ROTL
  o0 = x0; o1 = x1;
}

__device__ __forceinline__ float wave_sum(float v) {
#pragma unroll
  for (int o = 32; o > 0; o >>= 1) v += __shfl_xor(v, o, 64);
  return v;
}
__device__ __forceinline__ float wave_max(float v) {
#pragma unroll
  for (int o = 32; o > 0; o >>= 1) v = fmaxf(v, __shfl_xor(v, o, 64));
  return v;
}

__device__ __forceinline__ float gelu_f(float x) {
  float u = x / 1.4142135623730951f;
  float e = (float)erf((double)u);      // correctly-rounded f32 erf
  return x * (e + 1.0f) * 0.5f;
}

// ---------------------------------------------------------------------------
// fp32 tiled GEMM v2: C[M,N] = act(A[M,K] @ W[K,N] + bias) (+res)
// BM=BN=64, BK=32, 256 threads, 4x4 micro-tile, float4 LDS fragments.
// Accumulation order per output element: strictly k-ascending (== r4 kernel,
// bitwise-identical results).
// ---------------------------------------------------------------------------
template<int ACT, bool RES, bool CONCAT>
__device__ __forceinline__ void gemm_body(
    const float* __restrict__ A, const float* __restrict__ A2, int K1,
    const float* __restrict__ W, int ldw, const float* __restrict__ bias,
    const float* __restrict__ res, float* __restrict__ C, int N, int K)
{
  __shared__ alignas(16) float As[32][68];   // [kk][m], row = 272B (16B mult)
  __shared__ alignas(16) float Ws[32][68];   // [kk][n]
  const int bm = blockIdx.x * 64;
  const int bn = blockIdx.y * 64;
  const int tid = threadIdx.x;
  const int tr = (tid >> 4) << 2;   // fragment row (multiple of 4)
  const int tc = (tid & 15) << 2;   // fragment col (multiple of 4)
  // staging maps
  const int am = tid & 63;          // A row 0..63 (per-wave m spans 0..63 -> 2-way bank max)
  const int ak = (tid >> 6) << 3;   // A k-offset {0,8,16,24}
  const int wr = tid >> 3;          // W row 0..31
  const int wc = (tid & 7) << 3;    // W col {0,8,..,56}
  float acc[4][4] = {};
  for (int k0 = 0; k0 < K; k0 += 32) {
    // ---- stage A tile (64x32) ----
    {
      const int row = bm + am;
#pragma unroll
      for (int h = 0; h < 2; h++) {
        int gk = k0 + ak + 4 * h;
        float4 v;
        if (CONCAT) {
          v = (gk < K1) ? *(const float4*)&A[(size_t)row * K1 + gk]
                        : *(const float4*)&A2[(size_t)row * (K - K1) + (gk - K1)];
        } else {
          v = *(const float4*)&A[(size_t)row * K + gk];
        }
        int kb = ak + 4 * h;
        As[kb + 0][am] = v.x; As[kb + 1][am] = v.y;
        As[kb + 2][am] = v.z; As[kb + 3][am] = v.w;
      }
    }
    // ---- stage W tile (32x64) ----
    {
      const float* wsrc = &W[(size_t)(k0 + wr) * ldw + bn + wc];
      *(float4*)&Ws[wr][wc]     = *(const float4*)(wsrc);
      *(float4*)&Ws[wr][wc + 4] = *(const float4*)(wsrc + 4);
    }
    __syncthreads();
#pragma unroll
    for (int kk = 0; kk < 32; kk++) {
      float4 av = *(const float4*)&As[kk][tr];   // 4-way broadcast across lanes
      float4 bv = *(const float4*)&Ws[kk][tc];   // 4-way broadcast across lanes
      acc[0][0] = fmaf(av.x, bv.x, acc[0][0]);
      acc[0][1] = fmaf(av.x, bv.y, acc[0][1]);
      acc[0][2] = fmaf(av.x, bv.z, acc[0][2]);
      acc[0][3] = fmaf(av.x, bv.w, acc[0][3]);
      acc[1][0] = fmaf(av.y, bv.x, acc[1][0]);
      acc[1][1] = fmaf(av.y, bv.y, acc[1][1]);
      acc[1][2] = fmaf(av.y, bv.z, acc[1][2]);
      acc[1][3] = fmaf(av.y, bv.w, acc[1][3]);
      acc[2][0] = fmaf(av.z, bv.x, acc[2][0]);
      acc[2][1] = fmaf(av.z, bv.y, acc[2][1]);
      acc[2][2] = fmaf(av.z, bv.z, acc[2][2]);
      acc[2][3] = fmaf(av.z, bv.w, acc[2][3]);
      acc[3][0] = fmaf(av.w, bv.x, acc[3][0]);
      acc[3][1] = fmaf(av.w, bv.y, acc[3][1]);
      acc[3][2] = fmaf(av.w, bv.z, acc[3][2]);
      acc[3][3] = fmaf(av.w, bv.w, acc[3][3]);
    }
    __syncthreads();
  }
#pragma unroll
  for (int i = 0; i < 4; i++) {
    int m = bm + tr + i;
#pragma unroll
    for (int j = 0; j < 4; j++) {
      int n = bn + tc + j;
      float v = acc[i][j] + bias[n];
      if (ACT == 1) v = gelu_f(v);
      if (RES) v = v + res[(size_t)m * N + n];
      C[(size_t)m * N + n] = v;
    }
  }
}

template<int ACT, bool RES, bool CONCAT>
__global__ __launch_bounds__(256) void sgemm_k(
    const float* __restrict__ A, const float* __restrict__ A2, int K1,
    const float* __restrict__ W, int ldw, const float* __restrict__ bias,
    const float* __restrict__ res, float* __restrict__ C, int N, int K)
{
  gemm_body<ACT, RES, CONCAT>(A, A2, K1, W, ldw, bias, res, C, N, K);
}

// ---------------------------------------------------------------------------
// LayerNorm over D=512
// ---------------------------------------------------------------------------
template<bool AFFINE, bool ADD>
__global__ __launch_bounds__(256) void lnorm_k(
    const float* __restrict__ X, const float* __restrict__ X2,
    const float* __restrict__ g, const float* __restrict__ bt,
    float* __restrict__ Y)
{
  __shared__ float red[8];
  int row = blockIdx.x, tid = threadIdx.x;
  const float* x = X + (size_t)row * DD;
  float v0 = x[tid], v1 = x[tid + 256];
  if (ADD) {
    const float* x2 = X2 + (size_t)row * DD;
    v0 += x2[tid]; v1 += x2[tid + 256];
  }
  float s = wave_sum(v0 + v1);
  if ((tid & 63) == 0) red[tid >> 6] = s;
  __syncthreads();
  float mean = (red[0] + red[1] + red[2] + red[3]) * (1.0f / 512.0f);
  float d0 = v0 - mean, d1 = v1 - mean;
  float s2 = wave_sum(d0 * d0 + d1 * d1);
  if ((tid & 63) == 0) red[4 + (tid >> 6)] = s2;
  __syncthreads();
  float var = (red[4] + red[5] + red[6] + red[7]) * (1.0f / 512.0f);
  float rs = (float)(1.0 / sqrt((double)(var + 1e-5f)));
  float y0 = d0 * rs, y1 = d1 * rs;
  if (AFFINE) {
    y0 = y0 * g[tid] + bt[tid];
    y1 = y1 * g[tid + 256] + bt[tid + 256];
  }
  Y[(size_t)row * DD + tid] = y0;
  Y[(size_t)row * DD + tid + 256] = y1;
}

// ---------------------------------------------------------------------------
// GRU pointwise v2: gh side comes from a precomputed 50-row table
// (gh = emb[act] @ gwh + gbh; act<50 guaranteed by word mask). t==0: ix=0,
// gh=gbh. Reads previous action from out[]. Bitwise-identical values to the
// per-step GEMM (same weights, same k-order in the table build).
// ---------------------------------------------------------------------------
__global__ __launch_bounds__(256) void gru_pw2(
    const float* __restrict__ gi, const float* __restrict__ table,
    const float* __restrict__ gbh, const float* __restrict__ emb,
    const float* __restrict__ out, int t, float* __restrict__ hx)
{
  int idx = blockIdx.x * 256 + threadIdx.x;
  int b = idx >> 9, j = idx & 511;
  const float* ghb;
  float ixv;
  if (t == 0) {
    ghb = gbh;
    ixv = 0.f;
  } else {
    int a = (int)out[(size_t)b * TT + (t - 1)];
    ghb = table + (size_t)a * 1536;
    ixv = emb[(size_t)a * DD + j];
  }
  const float* gib = gi + (size_t)b * 1536;
  float r = (float)(1.0 / (1.0 + exp(-(double)(gib[j] + ghb[j]))));
  float z = (float)(1.0 / (1.0 + exp(-(double)(gib[DD + j] + ghb[DD + j]))));
  float narg = gib[2 * DD + j] + r * ghb[2 * DD + j];
  float n = (float)tanh((double)narg);
  hx[idx] = (1.0f - z) * n + z * ixv;
}

// ---------------------------------------------------------------------------
// Fused actor/critic heads + jax categorical sampling. 1 wave per row.
// ---------------------------------------------------------------------------
__global__ __launch_bounds__(64) void head_sample(
    const float* __restrict__ hx,
    const float* __restrict__ a1w, const float* __restrict__ a1b,
    const float* __restrict__ a2w, const float* __restrict__ a2b,
    const float* __restrict__ a3w, const float* __restrict__ a3b,
    const float* __restrict__ c1w, const float* __restrict__ c1b,
    const float* __restrict__ c2w, const float* __restrict__ c2b,
    const float* __restrict__ c3w, const float* __restrict__ c3b,
    const float* __restrict__ wmask,
    float* __restrict__ out,
    int t, uint32_t fk0, uint32_t fk1)
{
  int b = blockIdx.x;
  int lane = threadIdx.x;
  __shared__ float sh[DD];
  __shared__ float st1[64], st2[64], sc1[64];
  const float* hr = hx + (size_t)b * DD;
  for (int i = lane; i < DD; i += 64) sh[i] = hr[i];
  __syncthreads();

  float aa0 = 0, aa1 = 0, aa2 = 0, aa3 = 0, ca0 = 0, ca1 = 0, ca2 = 0, ca3 = 0;
  for (int k = 0; k < DD; k += 4) {
    float h0 = sh[k], h1 = sh[k + 1], h2 = sh[k + 2], h3 = sh[k + 3];
    aa0 = fmaf(h0, a1w[(k + 0) * 64 + lane], aa0);
    aa1 = fmaf(h1, a1w[(k + 1) * 64 + lane], aa1);
    aa2 = fmaf(h2, a1w[(k + 2) * 64 + lane], aa2);
    aa3 = fmaf(h3, a1w[(k + 3) * 64 + lane], aa3);
    ca0 = fmaf(h0, c1w[(k + 0) * 64 + lane], ca0);
    ca1 = fmaf(h1, c1w[(k + 1) * 64 + lane], ca1);
    ca2 = fmaf(h2, c1w[(k + 2) * 64 + lane], ca2);
    ca3 = fmaf(h3, c1w[(k + 3) * 64 + lane], ca3);
  }
  st1[lane] = (float)tanh((double)(((aa0 + aa1) + (aa2 + aa3)) + a1b[lane]));
  sc1[lane] = (float)tanh((double)(((ca0 + ca1) + (ca2 + ca3)) + c1b[lane]));
  __syncthreads();

  float a2acc = 0, c2acc = 0;
  for (int k = 0; k < 64; k++) {
    a2acc = fmaf(st1[k], a2w[k * 64 + lane], a2acc);
    c2acc = fmaf(sc1[k], c2w[k * 64 + lane], c2acc);
  }
  st2[lane] = (float)tanh((double)(a2acc + a2b[lane]));
  float t2c = (float)tanh((double)(c2acc + c2b[lane]));
  __syncthreads();

  float val = wave_sum(t2c * c3w[lane]) + c3b[0];

  float lg = -INFINITY;
  if (lane < NW) {
    float s = 0;
    for (int k = 0; k < 64; k++) s = fmaf(st2[k], a3w[k * VV + lane], s);
    lg = (s + a3b[lane]) + wmask[lane];
  }

  float m = wave_max(lg);
  float shf = 0.f, e = 0.f;
  if (lane < NW) { shf = lg - m; e = (float)exp((double)shf); }
  float se = wave_sum(e);
  float lse = (float)log((double)se);
  float logp = shf - lse;
  float term = 0.f;
  if (lane < NW) { float p = (float)exp((double)logp); term = p * logp; }
  float ent = -wave_sum(term);

  // gumbel: partitionable threefry, XOR fold (verified r4)
  float score = -INFINITY;
  if (lane < NW) {
    uint32_t i = (uint32_t)b * (uint32_t)VV + (uint32_t)lane;
    uint32_t o0, o1;
    tf2x32(fk0, fk1, 0u, i, o0, o1);
    uint32_t bits = o0 ^ o1;
    uint32_t mant = bits >> 9;
    float u = (mant == 0u) ? 1.17549435e-38f
                           : (float)mant * 1.1920928955078125e-7f;
    float l1 = (float)log((double)u);
    float l2 = (float)log((double)(-l1));
    score = -l2 + logp;
  }

  float best = score; int bi = lane;
#pragma unroll
  for (int off = 32; off > 0; off >>= 1) {
    float ob = __shfl_xor(best, off, 64);
    int oi = __shfl_xor(bi, off, 64);
    if (ob > best || (ob == best && oi < bi)) { best = ob; bi = oi; }
  }
  float lp = __shfl(logp, bi, 64);

  if (lane == 0) {
    out[(size_t)b * TT + t] = (float)bi;
    out[(size_t)BB * TT + (size_t)b * TT + t] = lp;
    out[2 * (size_t)BB * TT + (size_t)b * TT + t] = ent;
    out[3 * (size_t)BB * TT + (size_t)b * TT + t] = val;
  }
}

// ---------------------------------------------------------------------------
// Diagnostic channel (contract verified in r4; kept as a cheap guard)
// ---------------------------------------------------------------------------
__global__ __launch_bounds__(256) void diag_k(float* out, float code, int n) {
  int i = blockIdx.x * 256 + threadIdx.x;
  if (i < n) out[i] = code;
}

// ---------------------------------------------------------------------------
extern "C" void kernel_launch(void* const* d_in, const int* in_sizes, int n_in,
                              void* d_out, int out_size, void* d_ws, size_t ws_size,
                              hipStream_t stream) {
  static const int EXP_SIZES[34] = {
    2097152, 262144, 1179648, 512, 262144, 512, 262144, 512, 262144, 512,
    262144, 512, 512, 512, 262144, 512, 5120000, 786432, 786432, 1536,
    1536, 32768, 64, 4096, 64, 640000, 10000, 32768, 64, 4096,
    64, 64, 1, 10000 };
  double code = 0.0;
  if (n_in != 34) code = 1e6 + (double)n_in;
  else {
    for (int i = 0; i < 34; i++)
      if (in_sizes[i] != EXP_SIZES[i]) { code = 2e6 + i * 1e4 + (in_sizes[i] % 10000); break; }
  }
  if (code == 0.0 && out_size != 4 * BB * TT) code = 3e6 + (double)(out_size % 1000000);
  if (code == 0.0 && ws_size < (size_t)24 * 1024 * 1024) {
    size_t kb = ws_size / 1024; if (kb > 999999) kb = 999999;
    code = 4e6 + (double)kb;
  }
  if (code != 0.0) {
    diag_k<<<(out_size + 255) / 256, 256, 0, stream>>>((float*)d_out, (float)code, out_size);
    return;
  }

  const float* image = (const float*)d_in[0];
  const float* boxf  = (const float*)d_in[1];
  const float* fr_w  = (const float*)d_in[2];
  const float* fr_b  = (const float*)d_in[3];
  const float* d1a_w = (const float*)d_in[4];
  const float* d1a_b = (const float*)d_in[5];
  const float* d1b_w = (const float*)d_in[6];
  const float* d1b_b = (const float*)d_in[7];
  const float* d2a_w = (const float*)d_in[8];
  const float* d2a_b = (const float*)d_in[9];
  const float* d2b_w = (const float*)d_in[10];
  const float* d2b_b = (const float*)d_in[11];
  const float* ln_g  = (const float*)d_in[12];
  const float* ln_b  = (const float*)d_in[13];
  const float* eo_w  = (const float*)d_in[14];
  const float* eo_b  = (const float*)d_in[15];
  const float* emb   = (const float*)d_in[16];
  const float* gwi   = (const float*)d_in[17];
  const float* gwh   = (const float*)d_in[18];
  const float* gbi   = (const float*)d_in[19];
  const float* gbh   = (const float*)d_in[20];
  const float* a1w   = (const float*)d_in[21];
  const float* a1b   = (const float*)d_in[22];
  const float* a2w   = (const float*)d_in[23];
  const float* a2b   = (const float*)d_in[24];
  const float* a3w   = (const float*)d_in[25];
  const float* a3b   = (const float*)d_in[26];
  const float* c1w   = (const float*)d_in[27];
  const float* c1b   = (const float*)d_in[28];
  const float* c2w   = (const float*)d_in[29];
  const float* c2b   = (const float*)d_in[30];
  const float* c3w   = (const float*)d_in[31];
  const float* c3b   = (const float*)d_in[32];
  const float* wmask = (const float*)d_in[33];

  float* ws = (float*)d_ws;
  const size_t R = (size_t)BB * DD;          // 524288 floats
  float* hx    = ws;                          // [B,512]
  float* gi    = ws + R;                      // [B,1536]
  float* table = ws + 4 * R;                  // [64,1536] (rows 0..49 used + junk)
  // encoder scratch aliases gi region (dead before rollout GEMMs start):
  float* P = gi;              // x0
  float* Q = gi + R;          // tA
  float* S = gi + 2 * R;      // tB
  float* U = ws + 4 * R + 2 * R;  // y/x scratch (beyond table, < 24 MiB total)
  float* out = (float*)d_out;

  dim3 blk(256);
  // gh table: rows v<64 of emb @ gwh + gbh (only v<50 ever gathered)
  sgemm_k<0, false, false><<<dim3(1, 24), blk, 0, stream>>>(emb, nullptr, 0, gwh, 1536, gbh, nullptr, table, 1536, 512);
  // encoder
  sgemm_k<0, false, true><<<dim3(16, 8), blk, 0, stream>>>(image, boxf, 2048, fr_w, 512, fr_b, nullptr, P, 512, 2304);
  lnorm_k<false, false><<<BB, blk, 0, stream>>>(P, nullptr, nullptr, nullptr, Q);
  sgemm_k<1, false, false><<<dim3(16, 8), blk, 0, stream>>>(Q, nullptr, 0, d1a_w, 512, d1a_b, nullptr, S, 512, 512);
  sgemm_k<0, false, false><<<dim3(16, 8), blk, 0, stream>>>(S, nullptr, 0, d1b_w, 512, d1b_b, nullptr, U, 512, 512);
  lnorm_k<false, true><<<BB, blk, 0, stream>>>(U, P, nullptr, nullptr, Q);
  sgemm_k<1, false, false><<<dim3(16, 8), blk, 0, stream>>>(Q, nullptr, 0, d2a_w, 512, d2a_b, nullptr, S, 512, 512);
  sgemm_k<0, true, false><<<dim3(16, 8), blk, 0, stream>>>(S, nullptr, 0, d2b_w, 512, d2b_b, P, U, 512, 512);
  lnorm_k<true, false><<<BB, blk, 0, stream>>>(U, nullptr, ln_g, ln_b, Q);
  sgemm_k<0, false, false><<<dim3(16, 8), blk, 0, stream>>>(Q, nullptr, 0, eo_w, 512, eo_b, nullptr, hx, 512, 512);

  // rollout: gi = hx @ gwi + gbi ; gh/ix via table/emb gathers in gru_pw2
  for (int t = 0; t < TT; t++) {
    uint32_t fk0, fk1;
    tf2x32(0u, 1u, 0u, (uint32_t)t, fk0, fk1);   // fold_in(key(1), t)
    sgemm_k<0, false, false><<<dim3(16, 24), blk, 0, stream>>>(hx, nullptr, 0, gwi, 1536, gbi, nullptr, gi, 1536, 512);
    gru_pw2<<<2048, blk, 0, stream>>>(gi, table, gbh, emb, out, t, hx);
    head_sample<<<BB, dim3(64), 0, stream>>>(hx, a1w, a1b, a2w, a2b, a3w, a3b,
                                             c1w, c1b, c2w, c2b, c3w, c3b,
                                             wmask, out, t, fk0, fk1);
  }
}